// Round 1
// baseline (125.714 us; speedup 1.0000x reference)
//
#include <hip/hip_runtime.h>
#include <math.h>

#define OUT 260
#define IMG_H 2048
#define IMG_W 2048
#define NB 10
#define TH 0.8f

__device__ __forceinline__ float sincf(float x) {
    // jnp.sinc: sin(pi x)/(pi x), 1 at x==0
    if (x == 0.0f) return 1.0f;
    float px = 3.14159265358979323846f * x;
    return __sinf(px) / px;
}

__global__ __launch_bounds__(256) void crop_resize_kernel(
    const float* __restrict__ scores,
    const float* __restrict__ boxes,
    const float* __restrict__ img,
    float* __restrict__ out)
{
    const int p   = blockIdx.x;   // output row 0..259
    const int box = blockIdx.y;   // box 0..9

    const float b0 = boxes[box * 4 + 0];
    const float b1 = boxes[box * 4 + 1];
    const float b2 = boxes[box * 4 + 2];
    const float b3 = boxes[box * 4 + 3];

    // JAX astype(int32): truncation toward zero (all values >= 0 here)
    const int y0 = (int)(b0 * (float)IMG_H);
    const int x0 = (int)(b1 * (float)IMG_W);
    const int y1 = (int)(b2 * (float)IMG_H);
    const int x1 = (int)(b3 * (float)IMG_W);
    const int ch = max(y1 - y0, 1);
    const int cw = max(x1 - x0, 1);

    const bool valid = (scores[0] >= TH) && (scores[box] >= TH)
                    && (b1 >= 0.0f) && (b3 <= 1.0f);
    const float vmask = valid ? 1.0f : 0.0f;

    // ---- vertical taps/weights for this output row (block-uniform) ----
    float wh[6];
    int   ih[6];
    {
        const float src = ((float)p + 0.5f) * ((float)ch / (float)OUT) - 0.5f;
        const int base = (int)floorf(src) - 2;
        float s = 0.0f;
        #pragma unroll
        for (int a = 0; a < 6; ++a) {
            const int tap = base + a;
            const float d = src - (float)tap;
            const float w = (fabsf(d) < 3.0f) ? sincf(d) * sincf(d * (1.0f / 3.0f)) : 0.0f;
            wh[a] = w;
            s += w;
            int t = tap;
            t = t < 0 ? 0 : t;
            t = t > ch - 1 ? ch - 1 : t;          // clamp in crop-local space
            ih[a] = t + y0;                        // then shift by origin
        }
        const float inv = 1.0f / s;
        #pragma unroll
        for (int a = 0; a < 6; ++a) wh[a] *= inv;
    }

    const float wscale = (float)cw / (float)OUT;

    for (int q = threadIdx.x; q < OUT; q += blockDim.x) {
        // ---- horizontal taps/weights for this output column ----
        float ww[6];
        int   iw[6];
        {
            const float src = ((float)q + 0.5f) * wscale - 0.5f;
            const int base = (int)floorf(src) - 2;
            float s = 0.0f;
            #pragma unroll
            for (int b = 0; b < 6; ++b) {
                const int tap = base + b;
                const float d = src - (float)tap;
                const float w = (fabsf(d) < 3.0f) ? sincf(d) * sincf(d * (1.0f / 3.0f)) : 0.0f;
                ww[b] = w;
                s += w;
                int t = tap;
                t = t < 0 ? 0 : t;
                t = t > cw - 1 ? cw - 1 : t;
                iw[b] = (t + x0) * 3;              // byte-element offset within row
            }
            const float inv = 1.0f / s;
            #pragma unroll
            for (int b = 0; b < 6; ++b) ww[b] *= inv;
        }

        float acc0 = 0.0f, acc1 = 0.0f, acc2 = 0.0f;
        #pragma unroll
        for (int a = 0; a < 6; ++a) {
            const float* __restrict__ row = img + (size_t)ih[a] * (size_t)(IMG_W * 3);
            float r0 = 0.0f, r1 = 0.0f, r2 = 0.0f;
            #pragma unroll
            for (int b = 0; b < 6; ++b) {
                const float* __restrict__ px = row + iw[b];
                r0 = fmaf(ww[b], px[0], r0);
                r1 = fmaf(ww[b], px[1], r1);
                r2 = fmaf(ww[b], px[2], r2);
            }
            acc0 = fmaf(wh[a], r0, acc0);
            acc1 = fmaf(wh[a], r1, acc1);
            acc2 = fmaf(wh[a], r2, acc2);
        }

        const size_t o = (((size_t)box * OUT + p) * OUT + q) * 3;
        out[o + 0] = acc0 * vmask;
        out[o + 1] = acc1 * vmask;
        out[o + 2] = acc2 * vmask;
    }
}

extern "C" void kernel_launch(void* const* d_in, const int* in_sizes, int n_in,
                              void* d_out, int out_size, void* d_ws, size_t ws_size,
                              hipStream_t stream) {
    const float* scores = (const float*)d_in[0];   // (100,)
    const float* boxes  = (const float*)d_in[1];   // (100,4)
    const float* img    = (const float*)d_in[2];   // (1,2048,2048,3)
    float* out = (float*)d_out;                    // (10,260,260,3)

    dim3 grid(OUT, NB);
    crop_resize_kernel<<<grid, dim3(256), 0, stream>>>(scores, boxes, img, out);
}